// Round 8
// baseline (81.690 us; speedup 1.0000x reference)
//
#include <hip/hip_runtime.h>

// FK object-translation scan, round 8: T-parallel typed affine maps,
// register-pressure surgery (kill scratch spill seen as WRITE_SIZE 49MB).
//  - amdgpu_waves_per_eu(4,4): exactly 4 waves/EU (= max useful at grid
//    512 blocks x 8 waves = 2 blocks/CU), VGPR budget 128.
//  - KS scan composes IN PLACE under exec-mask (no Om[24], no selects).
//  - Cross-wave prefix applies wave-total maps (from LDS) to the concrete
//    (p,W) state vector instead of composing 24-float maps.
// Algorithm identical to rounds 6/7 (passed, absmax 0.5 vs threshold 3.18).

#define FSM_ID 0x24  // identity: 0->0,1->1,2->2 (2 bits per state image)

__device__ __forceinline__ int fsm_compose(int f, int g) {  // g first, then f
    int r0 = (f >> (((g     ) & 3) << 1)) & 3;
    int r1 = (f >> (((g >> 2) & 3) << 1)) & 3;
    int r2 = (f >> (((g >> 4) & 3) << 1)) & 3;
    return r0 | (r1 << 2) | (r2 << 4);
}

// typed map: Mp[0..8], cp[9..11], Mw[12..20], cw[21..23]; tags rp,rw (0=p,1=w)
__device__ __forceinline__ void tmap_identity(float* m, int& rp, int& rw) {
    #pragma unroll
    for (int i = 0; i < 24; ++i) m[i] = 0.f;
    m[0] = m[4] = m[8] = 1.f;
    m[12] = m[16] = m[20] = 1.f;
    rp = 0; rw = 1;
}

// L <- L o E (E applied first), in place on L.
__device__ __forceinline__ void tmap_compose_inplace(
    float* Lm, int& Lrp, int& Lrw,
    const float* Em, int Erp, int Erw)
{
    {   // p-block
        float EM[9], Ec[3];
        #pragma unroll
        for (int i = 0; i < 9; ++i) EM[i] = Lrp ? Em[12+i] : Em[i];
        #pragma unroll
        for (int i = 0; i < 3; ++i) Ec[i] = Lrp ? Em[21+i] : Em[9+i];
        #pragma unroll
        for (int i = 0; i < 3; ++i) {
            const float a = Lm[3*i], b = Lm[3*i+1], c = Lm[3*i+2];
            Lm[3*i+0] = a*EM[0] + b*EM[3] + c*EM[6];
            Lm[3*i+1] = a*EM[1] + b*EM[4] + c*EM[7];
            Lm[3*i+2] = a*EM[2] + b*EM[5] + c*EM[8];
            Lm[9+i]  += a*Ec[0] + b*Ec[1] + c*Ec[2];
        }
    }
    {   // w-block
        float EM[9], Ec[3];
        #pragma unroll
        for (int i = 0; i < 9; ++i) EM[i] = Lrw ? Em[12+i] : Em[i];
        #pragma unroll
        for (int i = 0; i < 3; ++i) Ec[i] = Lrw ? Em[21+i] : Em[9+i];
        #pragma unroll
        for (int i = 0; i < 3; ++i) {
            const float a = Lm[12+3*i], b = Lm[12+3*i+1], c = Lm[12+3*i+2];
            Lm[12+3*i+0] = a*EM[0] + b*EM[3] + c*EM[6];
            Lm[12+3*i+1] = a*EM[1] + b*EM[4] + c*EM[7];
            Lm[12+3*i+2] = a*EM[2] + b*EM[5] + c*EM[8];
            Lm[21+i]    += a*Ec[0] + b*Ec[1] + c*Ec[2];
        }
    }
    const int nrp = Lrp ? Erw : Erp;
    const int nrw = Lrw ? Erw : Erp;
    Lrp = nrp; Lrw = nrw;
}

// apply map m (tags rp_,rw_) to state (pin,win) -> (pout,wout); m may be LDS.
__device__ __forceinline__ void tmap_apply(
    const float* m, int rp_, int rw_,
    const float* pin, const float* win, float* pout, float* wout)
{
    const float* ip = rp_ ? win : pin;
    pout[0] = m[0]*ip[0] + m[1]*ip[1] + m[2]*ip[2] + m[9];
    pout[1] = m[3]*ip[0] + m[4]*ip[1] + m[5]*ip[2] + m[10];
    pout[2] = m[6]*ip[0] + m[7]*ip[1] + m[8]*ip[2] + m[11];
    const float* iw = rw_ ? win : pin;
    wout[0] = m[12]*iw[0] + m[13]*iw[1] + m[14]*iw[2] + m[21];
    wout[1] = m[15]*iw[0] + m[16]*iw[1] + m[17]*iw[2] + m[22];
    wout[2] = m[18]*iw[0] + m[19]*iw[1] + m[20]*iw[2] + m[23];
}

__global__ void __launch_bounds__(512)
__attribute__((amdgpu_waves_per_eu(4, 4)))
fk_scan_par4(
    const float* __restrict__ prob,   // (B,4096,2)
    const float* __restrict__ hands,  // (B,4096,2,3)
    const float* __restrict__ rotm,   // (B,4096,3,3)
    const float* __restrict__ tinit,  // (B,3)
    float* __restrict__ out)          // (B,4096,3)
{
    const int b    = blockIdx.x;
    const int c    = threadIdx.x;     // chunk id 0..511, 8 steps each
    const int lane = c & 63;
    const int w    = c >> 6;          // wave 0..7

    __shared__ int   sFSM[8];
    __shared__ float sAm[8][24];
    __shared__ int   sAf[8];

    const float* prB = prob  + (size_t)b * 4096 * 2;
    const float* hdB = hands + (size_t)b * 4096 * 6;
    const float* rmB = rotm  + (size_t)b * 4096 * 9;
    float*       obB = out   + (size_t)b * 4096 * 3;

    const float4* pr4 = (const float4*)prB + c * 4;    // 8 steps * 2 / 4
    const float4* hd4 = (const float4*)hdB + c * 12;   // 8 steps * 6 / 4
    const float4* rm4 = (const float4*)rmB + c * 18;   // 8 steps * 9 / 4
    float4*       ob4 = (float4*)obB       + c * 6;    // 8 steps * 3 / 4

    // ---------------- P1: pack 8 contact bits ----------------
    unsigned lcB = 0, rcB = 0;
    #pragma unroll
    for (int i = 0; i < 4; ++i) {
        float4 v = pr4[i];
        lcB |= (unsigned)(v.x > 0.5f) << (2*i);
        rcB |= (unsigned)(v.y > 0.5f) << (2*i);
        lcB |= (unsigned)(v.z > 0.5f) << (2*i+1);
        rcB |= (unsigned)(v.w > 0.5f) << (2*i+1);
    }
    unsigned pL = 0, pR = 0;
    if (c) {
        float2 pv = *(const float2*)(prB + 16*c - 2);  // step 8c-1
        pL = pv.x > 0.5f ? 1u : 0u;
        pR = pv.y > 0.5f ? 1u : 0u;
    }
    unsigned lsB = lcB & ~((lcB << 1) | pL);
    unsigned rsB = rcB & ~((rcB << 1) | pR);
    if (c == 0) { lcB &= ~1u; rcB &= ~1u; lsB &= ~1u; rsB &= ~1u; } // t=0 forced false

    // ---------------- P1b: FSM compose + hierarchical scan ----------------
    int M = FSM_ID;
    #pragma unroll
    for (int k = 0; k < 8; ++k) {
        const unsigned lc = (lcB >> k) & 1u, rc = (rcB >> k) & 1u;
        const unsigned ls = (lsB >> k) & 1u, rs = (rsB >> k) & 1u;
        const int nwi = (int)(ls | rs);
        const int nwe = ls ? 1 : 2;
        const int e0  = lc ? 1 : (rc ? 2 : 0);
        const int e1  = rc ? 2 : (lc ? 1 : 0);
        const int mt  = nwi ? nwe * 0x15 : ((e0 << 2) | (e1 << 4));
        M = fsm_compose(mt, M);
    }
    #pragma unroll
    for (int d = 1; d < 64; d <<= 1) {
        int v  = __shfl_up(M, d);
        int cc = fsm_compose(M, v);
        M = (lane >= d) ? cc : M;
    }
    if (lane == 63) sFSM[w] = M;
    __syncthreads();
    int Pf = FSM_ID;
    for (int i = 0; i < w; ++i) Pf = fsm_compose(sFSM[i], Pf);
    int Me = __shfl_up(M, 1);
    if (lane == 0) Me = FSM_ID;
    const int s_in = fsm_compose(Me, Pf) & 3;   // applied to initial state 0 (cur=-1)

    // ---------------- P2: typed affine compose over 8 steps ----------------
    float Am[24]; int rp, rw;
    tmap_identity(Am, rp, rw);
    int s = s_in;
    #pragma unroll
    for (int g = 0; g < 2; ++g) {
        // batched, unconditional group loads (one latency stall per group)
        float rb[36], hb[24];
        #pragma unroll
        for (int j = 0; j < 9; ++j) {
            float4 v = rm4[g*9 + j];
            rb[4*j]=v.x; rb[4*j+1]=v.y; rb[4*j+2]=v.z; rb[4*j+3]=v.w;
        }
        #pragma unroll
        for (int j = 0; j < 6; ++j) {
            float4 v = hd4[g*6 + j];
            hb[4*j]=v.x; hb[4*j+1]=v.y; hb[4*j+2]=v.z; hb[4*j+3]=v.w;
        }
        #pragma unroll
        for (int j = 0; j < 4; ++j) {
            const int k = 4*g + j;
            const unsigned lc=(lcB>>k)&1u, rc=(rcB>>k)&1u;
            const unsigned ls=(lsB>>k)&1u, rs=(rsB>>k)&1u;
            const int nwi  = (int)(ls|rs);
            const int c1 = (s==1), c2 = (s==2);
            const int hasc = (c1&(int)lc)|(c2&(int)rc);
            const int haso = (c1&(int)rc)|(c2&(int)lc);
            const int grab = nwi | ((hasc^1)&haso);
            const int gi   = nwi ? (ls?0:1) : c1;
            const int new_s= grab ? gi+1 : (hasc ? s : 0);
            const float* Rk = rb + 9*j;
            const float* Hk = hb + 6*j;
            if (grab) {
                const float hx = gi?Hk[3]:Hk[0], hy = gi?Hk[4]:Hk[1], hz = gi?Hk[5]:Hk[2];
                // Wmap <- R^T o pmap; cw = R^T (cp - h); rw = rp  (p'~=p approx)
                float t[9];
                #pragma unroll
                for (int i2=0;i2<3;++i2)
                    #pragma unroll
                    for (int j2=0;j2<3;++j2)
                        t[3*i2+j2] = Rk[i2]*Am[j2] + Rk[3+i2]*Am[3+j2] + Rk[6+i2]*Am[6+j2];
                const float ex=Am[9]-hx, ey=Am[10]-hy, ez=Am[11]-hz;
                Am[21] = Rk[0]*ex + Rk[3]*ey + Rk[6]*ez;
                Am[22] = Rk[1]*ex + Rk[4]*ey + Rk[7]*ez;
                Am[23] = Rk[2]*ex + Rk[5]*ey + Rk[8]*ez;
                #pragma unroll
                for (int i2=0;i2<9;++i2) Am[12+i2] = t[i2];
                rw = rp;
            } else if (new_s) {
                const int ci = new_s - 1;
                const float hx = ci?Hk[3]:Hk[0], hy = ci?Hk[4]:Hk[1], hz = ci?Hk[5]:Hk[2];
                // pmap <- h + R o Wmap; rp = rw
                float t[9];
                #pragma unroll
                for (int i2=0;i2<3;++i2)
                    #pragma unroll
                    for (int j2=0;j2<3;++j2)
                        t[3*i2+j2] = Rk[3*i2]*Am[12+j2] + Rk[3*i2+1]*Am[15+j2] + Rk[3*i2+2]*Am[18+j2];
                const float e0_ = hx + Rk[0]*Am[21] + Rk[1]*Am[22] + Rk[2]*Am[23];
                const float e1_ = hy + Rk[3]*Am[21] + Rk[4]*Am[22] + Rk[5]*Am[23];
                const float e2_ = hz + Rk[6]*Am[21] + Rk[7]*Am[22] + Rk[8]*Am[23];
                #pragma unroll
                for (int i2=0;i2<9;++i2) Am[i2] = t[i2];
                Am[9]=e0_; Am[10]=e1_; Am[11]=e2_;
                rp = rw;
            }
            s = new_s;
        }
    }

    // ---------------- affine KS scan (in-place, exec-masked) ---------------
    #pragma unroll
    for (int d = 1; d < 64; d <<= 1) {
        float Em[24];
        #pragma unroll
        for (int i = 0; i < 24; ++i) Em[i] = __shfl_up(Am[i], d);
        const int Ef = __shfl_up(rp | (rw<<1), d);
        if (lane >= d)
            tmap_compose_inplace(Am, rp, rw, Em, Ef & 1, (Ef >> 1) & 1);
    }
    if (lane == 63) {
        #pragma unroll
        for (int i = 0; i < 24; ++i) sAm[w][i] = Am[i];
        sAf[w] = rp | (rw<<1);
    }
    __syncthreads();

    // exclusive shift in place: Am <- prefix of lanes [0, lane)
    {
        #pragma unroll
        for (int i = 0; i < 24; ++i) Am[i] = __shfl_up(Am[i], 1);
        const int t = __shfl_up(rp | (rw<<1), 1);
        rp = t & 1; rw = (t >> 1) & 1;
        if (lane == 0) tmap_identity(Am, rp, rw);
    }

    // wave prefix applied to the concrete state vector (p0=tinit, W0=0)
    float vp[3] = { tinit[3*b], tinit[3*b+1], tinit[3*b+2] };
    float vw[3] = { 0.f, 0.f, 0.f };
    for (int i = 0; i < w; ++i) {
        float np[3], nw2[3];
        const int f = sAf[i];
        tmap_apply(&sAm[i][0], f & 1, (f >> 1) & 1, vp, vw, np, nw2);
        vp[0]=np[0]; vp[1]=np[1]; vp[2]=np[2];
        vw[0]=nw2[0]; vw[1]=nw2[1]; vw[2]=nw2[2];
    }
    float pv[3], wv[3];
    tmap_apply(Am, rp, rw, vp, vw, pv, wv);
    float px = pv[0], py = pv[1], pz = pv[2];
    float Wx = wv[0], Wy = wv[1], Wz = wv[2];

    // ---------------- P3: exact replay + output ----------------
    s = s_in;
    #pragma unroll
    for (int g = 0; g < 2; ++g) {
        float rb[36], hb[24];
        #pragma unroll
        for (int j = 0; j < 9; ++j) {
            float4 v = rm4[g*9 + j];
            rb[4*j]=v.x; rb[4*j+1]=v.y; rb[4*j+2]=v.z; rb[4*j+3]=v.w;
        }
        #pragma unroll
        for (int j = 0; j < 6; ++j) {
            float4 v = hd4[g*6 + j];
            hb[4*j]=v.x; hb[4*j+1]=v.y; hb[4*j+2]=v.z; hb[4*j+3]=v.w;
        }
        float o[12];
        #pragma unroll
        for (int j = 0; j < 4; ++j) {
            const int k = 4*g + j;
            const unsigned lc=(lcB>>k)&1u, rc=(rcB>>k)&1u;
            const unsigned ls=(lsB>>k)&1u, rs=(rsB>>k)&1u;
            const int nwi  = (int)(ls|rs);
            const int c1 = (s==1), c2 = (s==2);
            const int hasc = (c1&(int)lc)|(c2&(int)rc);
            const int haso = (c1&(int)rc)|(c2&(int)lc);
            const int grab = nwi | ((hasc^1)&haso);
            const int gi   = nwi ? (ls?0:1) : c1;
            const int new_s= grab ? gi+1 : (hasc ? s : 0);
            const float* Rk = rb + 9*j;
            const float* Hk = hb + 6*j;
            if (grab) {
                const float hx = gi?Hk[3]:Hk[0], hy = gi?Hk[4]:Hk[1], hz = gi?Hk[5]:Hk[2];
                const float vx = px-hx, vy = py-hy, vz = pz-hz;
                const float d2 = vx*vx + vy*vy + vz*vz;
                if (d2 > 1e-12f) {
                    Wx = Rk[0]*vx + Rk[3]*vy + Rk[6]*vz;
                    Wy = Rk[1]*vx + Rk[4]*vy + Rk[7]*vz;
                    Wz = Rk[2]*vx + Rk[5]*vy + Rk[8]*vz;
                } else {
                    Wx = 0.1f*Rk[6]; Wy = 0.1f*Rk[7]; Wz = 0.1f*Rk[8];
                }
            }
            if (new_s) {
                const int ci = new_s - 1;
                const float hx = ci?Hk[3]:Hk[0], hy = ci?Hk[4]:Hk[1], hz = ci?Hk[5]:Hk[2];
                px = hx + Rk[0]*Wx + Rk[1]*Wy + Rk[2]*Wz;
                py = hy + Rk[3]*Wx + Rk[4]*Wy + Rk[5]*Wz;
                pz = hz + Rk[6]*Wx + Rk[7]*Wy + Rk[8]*Wz;
            }
            s = new_s;
            o[3*j+0]=px; o[3*j+1]=py; o[3*j+2]=pz;
        }
        ob4[g*3+0] = make_float4(o[0], o[1], o[2],  o[3]);
        ob4[g*3+1] = make_float4(o[4], o[5], o[6],  o[7]);
        ob4[g*3+2] = make_float4(o[8], o[9], o[10], o[11]);
    }
}

// ---------------- fallback (any T): wave-per-batch serial scan -----
#define CT 256
__global__ __launch_bounds__(64) void fk_scan_wave(
    const float* __restrict__ prob, const float* __restrict__ hands,
    const float* __restrict__ rotm, const float* __restrict__ tinit,
    float* __restrict__ out, int B, int T)
{
    __shared__ __align__(16) float sP[CT * 2];
    __shared__ __align__(16) float sH[CT * 8];
    __shared__ __align__(16) float sR[CT * 12];
    const int b = blockIdx.x, lane = threadIdx.x;
    const float* prB = prob  + (size_t)b * T * 2;
    const float* hdB = hands + (size_t)b * T * 6;
    const float* rmB = rotm  + (size_t)b * T * 9;
    float*       obB = out   + (size_t)b * T * 3;
    float px = tinit[3*b+0], py = tinit[3*b+1], pz = tinit[3*b+2];
    float Wx = 0.f, Wy = 0.f, Wz = 0.f;
    int cur = -1, prev_l = 0, prev_r = 0;
    for (int t0 = 0; t0 < T; t0 += CT) {
        const int n = (T - t0 < CT) ? (T - t0) : CT;
        for (int i = lane; i < n * 2; i += 64) sP[i] = prB[(size_t)t0*2 + i];
        for (int i = lane; i < n * 6; i += 64) {
            int s2 = i / 6, cc = i - 6*s2; sH[8*s2+cc] = hdB[(size_t)t0*6 + i];
        }
        for (int i = lane; i < n * 9; i += 64) {
            int s2 = i / 9, cc = i - 9*s2; sR[12*s2+cc] = rmB[(size_t)t0*9 + i];
        }
        __syncthreads();
        for (int k = 0; k < n; ++k) {
            const int t = t0 + k;
            const int rl = __builtin_amdgcn_readfirstlane(sP[2*k]   > 0.5f ? 1 : 0);
            const int rr = __builtin_amdgcn_readfirstlane(sP[2*k+1] > 0.5f ? 1 : 0);
            const int nz = (t != 0) ? 1 : 0;
            const int l_c = rl & nz, r_c = rr & nz;
            const int l_s = rl & (prev_l ^ 1) & nz, r_s = rr & (prev_r ^ 1) & nz;
            prev_l = rl; prev_r = rr;
            const int nw = l_s ? 0 : (r_s ? 1 : -1);
            const int hasc = ((cur==0)&l_c) | ((cur==1)&r_c);
            const int haso = ((cur==0)&r_c) | ((cur==1)&l_c);
            const int grab = (nw != -1) | ((hasc^1)&haso);
            const int new_cur = grab ? ((nw!=-1)?nw:(1-cur))
                                     : (((hasc^1)&(cur!=-1)) ? -1 : cur);
            if (new_cur != -1) {
                const float h0x=sH[8*k+0],h0y=sH[8*k+1],h0z=sH[8*k+2];
                const float h1x=sH[8*k+3],h1y=sH[8*k+4],h1z=sH[8*k+5];
                const float R0=sR[12*k+0],R1=sR[12*k+1],R2=sR[12*k+2];
                const float R3=sR[12*k+3],R4=sR[12*k+4],R5=sR[12*k+5];
                const float R6=sR[12*k+6],R7=sR[12*k+7],R8=sR[12*k+8];
                const float hx = new_cur ? h1x : h0x;
                const float hy = new_cur ? h1y : h0y;
                const float hz = new_cur ? h1z : h0z;
                if (grab) {
                    const float vx=px-hx, vy=py-hy, vz=pz-hz;
                    const float d2 = vx*vx+vy*vy+vz*vz;
                    if (d2 > 1e-12f) {
                        Wx = R0*vx+R3*vy+R6*vz; Wy = R1*vx+R4*vy+R7*vz; Wz = R2*vx+R5*vy+R8*vz;
                    } else { Wx = 0.1f*R6; Wy = 0.1f*R7; Wz = 0.1f*R8; }
                }
                px = hx + (R0*Wx+R1*Wy+R2*Wz);
                py = hy + (R3*Wx+R4*Wy+R5*Wz);
                pz = hz + (R6*Wx+R7*Wy+R8*Wz);
            }
            cur = new_cur;
            if (lane == 0) {
                obB[3*(size_t)t+0]=px; obB[3*(size_t)t+1]=py; obB[3*(size_t)t+2]=pz;
            }
        }
        __syncthreads();
    }
}

extern "C" void kernel_launch(void* const* d_in, const int* in_sizes, int n_in,
                              void* d_out, int out_size, void* d_ws, size_t ws_size,
                              hipStream_t stream) {
    const float* prob  = (const float*)d_in[0];
    const float* hands = (const float*)d_in[1];
    const float* rotm  = (const float*)d_in[2];
    const float* tinit = (const float*)d_in[3];
    float* out = (float*)d_out;

    const int B = in_sizes[3] / 3;
    const int T = in_sizes[0] / (B * 2);

    if (T == 4096) {
        hipLaunchKernelGGL(fk_scan_par4, dim3(B), dim3(512), 0, stream,
                           prob, hands, rotm, tinit, out);
    } else {
        hipLaunchKernelGGL(fk_scan_wave, dim3(B), dim3(64), 0, stream,
                           prob, hands, rotm, tinit, out, B, T);
    }
}

// Round 9
// 61.709 us; speedup vs baseline: 1.3238x; 1.3238x over previous
//
#include <hip/hip_runtime.h>

// FK object-translation scan, round 9: T-parallel typed affine maps,
// 1024 threads/block (16 waves), 4 steps/thread.
//  - Halves r7's per-thread serial chains (P2 compose, P3 replay, loads).
//  - 8192 waves total -> up to 8 waves/SIMD at 64 VGPR: max TLP for latency.
//  - KS scan uses r7's select-based compose (register-friendly codegen;
//    r8's exec-masked in-place variant forced Am to memory -> regression).
//  - Cross-wave prefix: 16 wave-totals in LDS, applied to the concrete
//    (p,W) state vector (cheap, no map-map composition in the epilogue).
// Algorithm identical to rounds 6-8 (passed, absmax 0.5 vs threshold 3.18).

#define FSM_ID 0x24  // identity: 0->0,1->1,2->2 (2 bits per state image)

__device__ __forceinline__ int fsm_compose(int f, int g) {  // g first, then f
    int r0 = (f >> (((g     ) & 3) << 1)) & 3;
    int r1 = (f >> (((g >> 2) & 3) << 1)) & 3;
    int r2 = (f >> (((g >> 4) & 3) << 1)) & 3;
    return r0 | (r1 << 2) | (r2 << 4);
}

// typed map: Mp[0..8], cp[9..11], Mw[12..20], cw[21..23]; tags rp,rw (0=p,1=w)
__device__ __forceinline__ void tmap_identity(float* m, int& rp, int& rw) {
    #pragma unroll
    for (int i = 0; i < 24; ++i) m[i] = 0.f;
    m[0] = m[4] = m[8] = 1.f;
    m[12] = m[16] = m[20] = 1.f;
    rp = 0; rw = 1;
}

// Om = L o E (E applied first), out of place (select-friendly codegen).
__device__ __forceinline__ void tmap_compose(
    const float* Lm, int Lrp, int Lrw,
    const float* Em, int Erp, int Erw,
    float* Om, int& Orp, int& Orw)
{
    {   // p-output
        float EM[9], Ec[3];
        #pragma unroll
        for (int i = 0; i < 9; ++i) EM[i] = Lrp ? Em[12+i] : Em[i];
        #pragma unroll
        for (int i = 0; i < 3; ++i) Ec[i] = Lrp ? Em[21+i] : Em[9+i];
        #pragma unroll
        for (int i = 0; i < 3; ++i) {
            #pragma unroll
            for (int j = 0; j < 3; ++j)
                Om[3*i+j] = Lm[3*i]*EM[j] + Lm[3*i+1]*EM[3+j] + Lm[3*i+2]*EM[6+j];
            Om[9+i] = Lm[3*i]*Ec[0] + Lm[3*i+1]*Ec[1] + Lm[3*i+2]*Ec[2] + Lm[9+i];
        }
        Orp = Lrp ? Erw : Erp;
    }
    {   // w-output
        float EM[9], Ec[3];
        #pragma unroll
        for (int i = 0; i < 9; ++i) EM[i] = Lrw ? Em[12+i] : Em[i];
        #pragma unroll
        for (int i = 0; i < 3; ++i) Ec[i] = Lrw ? Em[21+i] : Em[9+i];
        #pragma unroll
        for (int i = 0; i < 3; ++i) {
            #pragma unroll
            for (int j = 0; j < 3; ++j)
                Om[12+3*i+j] = Lm[12+3*i]*EM[j] + Lm[12+3*i+1]*EM[3+j] + Lm[12+3*i+2]*EM[6+j];
            Om[21+i] = Lm[12+3*i]*Ec[0] + Lm[12+3*i+1]*Ec[1] + Lm[12+3*i+2]*Ec[2] + Lm[21+i];
        }
        Orw = Lrw ? Erw : Erp;
    }
}

// apply map m (tags rp_,rw_) to state (pin,win) -> (pout,wout); m may be LDS.
__device__ __forceinline__ void tmap_apply(
    const float* m, int rp_, int rw_,
    const float* pin, const float* win, float* pout, float* wout)
{
    const float* ip = rp_ ? win : pin;
    pout[0] = m[0]*ip[0] + m[1]*ip[1] + m[2]*ip[2] + m[9];
    pout[1] = m[3]*ip[0] + m[4]*ip[1] + m[5]*ip[2] + m[10];
    pout[2] = m[6]*ip[0] + m[7]*ip[1] + m[8]*ip[2] + m[11];
    const float* iw = rw_ ? win : pin;
    wout[0] = m[12]*iw[0] + m[13]*iw[1] + m[14]*iw[2] + m[21];
    wout[1] = m[15]*iw[0] + m[16]*iw[1] + m[17]*iw[2] + m[22];
    wout[2] = m[18]*iw[0] + m[19]*iw[1] + m[20]*iw[2] + m[23];
}

__global__ __launch_bounds__(1024) void fk_scan_par5(
    const float* __restrict__ prob,   // (B,4096,2)
    const float* __restrict__ hands,  // (B,4096,2,3)
    const float* __restrict__ rotm,   // (B,4096,3,3)
    const float* __restrict__ tinit,  // (B,3)
    float* __restrict__ out)          // (B,4096,3)
{
    const int b    = blockIdx.x;
    const int c    = threadIdx.x;     // chunk id 0..1023, 4 steps each
    const int lane = c & 63;
    const int w    = c >> 6;          // wave 0..15

    __shared__ int   sFSM[16];
    __shared__ float sAm[16][24];
    __shared__ int   sAf[16];

    const float* prB = prob  + (size_t)b * 4096 * 2;
    const float* hdB = hands + (size_t)b * 4096 * 6;
    const float* rmB = rotm  + (size_t)b * 4096 * 9;
    float*       obB = out   + (size_t)b * 4096 * 3;

    const float4* pr4 = (const float4*)prB + c * 2;    // 4 steps * 2 / 4
    const float4* hd4 = (const float4*)hdB + c * 6;    // 4 steps * 6 / 4
    const float4* rm4 = (const float4*)rmB + c * 9;    // 4 steps * 9 / 4
    float4*       ob4 = (float4*)obB       + c * 3;    // 4 steps * 3 / 4

    // ---------------- P1: pack 4 contact bits ----------------
    unsigned lcB = 0, rcB = 0;
    #pragma unroll
    for (int i = 0; i < 2; ++i) {
        float4 v = pr4[i];
        lcB |= (unsigned)(v.x > 0.5f) << (2*i);
        rcB |= (unsigned)(v.y > 0.5f) << (2*i);
        lcB |= (unsigned)(v.z > 0.5f) << (2*i+1);
        rcB |= (unsigned)(v.w > 0.5f) << (2*i+1);
    }
    unsigned pL = 0, pR = 0;
    if (c) {
        float2 pv = *(const float2*)(prB + 8*c - 2);   // step 4c-1
        pL = pv.x > 0.5f ? 1u : 0u;
        pR = pv.y > 0.5f ? 1u : 0u;
    }
    unsigned lsB = lcB & ~((lcB << 1) | pL);
    unsigned rsB = rcB & ~((rcB << 1) | pR);
    if (c == 0) { lcB &= ~1u; rcB &= ~1u; lsB &= ~1u; rsB &= ~1u; } // t=0 forced false

    // ---------------- P1b: FSM compose + hierarchical scan ----------------
    int M = FSM_ID;
    #pragma unroll
    for (int k = 0; k < 4; ++k) {
        const unsigned lc = (lcB >> k) & 1u, rc = (rcB >> k) & 1u;
        const unsigned ls = (lsB >> k) & 1u, rs = (rsB >> k) & 1u;
        const int nwi = (int)(ls | rs);
        const int nwe = ls ? 1 : 2;
        const int e0  = lc ? 1 : (rc ? 2 : 0);
        const int e1  = rc ? 2 : (lc ? 1 : 0);
        const int mt  = nwi ? nwe * 0x15 : ((e0 << 2) | (e1 << 4));
        M = fsm_compose(mt, M);
    }
    #pragma unroll
    for (int d = 1; d < 64; d <<= 1) {
        int v  = __shfl_up(M, d);
        int cc = fsm_compose(M, v);
        M = (lane >= d) ? cc : M;
    }
    if (lane == 63) sFSM[w] = M;
    __syncthreads();
    int Pf = FSM_ID;
    for (int i = 0; i < w; ++i) Pf = fsm_compose(sFSM[i], Pf);
    int Me = __shfl_up(M, 1);
    if (lane == 0) Me = FSM_ID;
    const int s_in = fsm_compose(Me, Pf) & 3;   // applied to initial state 0 (cur=-1)

    // ---------------- P2: typed affine compose over 4 steps ----------------
    float Am[24]; int rp, rw;
    tmap_identity(Am, rp, rw);
    int s = s_in;
    {
        float rb[36], hb[24];
        #pragma unroll
        for (int j = 0; j < 9; ++j) {
            float4 v = rm4[j];
            rb[4*j]=v.x; rb[4*j+1]=v.y; rb[4*j+2]=v.z; rb[4*j+3]=v.w;
        }
        #pragma unroll
        for (int j = 0; j < 6; ++j) {
            float4 v = hd4[j];
            hb[4*j]=v.x; hb[4*j+1]=v.y; hb[4*j+2]=v.z; hb[4*j+3]=v.w;
        }
        #pragma unroll
        for (int k = 0; k < 4; ++k) {
            const unsigned lc=(lcB>>k)&1u, rc=(rcB>>k)&1u;
            const unsigned ls=(lsB>>k)&1u, rs=(rsB>>k)&1u;
            const int nwi  = (int)(ls|rs);
            const int c1 = (s==1), c2 = (s==2);
            const int hasc = (c1&(int)lc)|(c2&(int)rc);
            const int haso = (c1&(int)rc)|(c2&(int)lc);
            const int grab = nwi | ((hasc^1)&haso);
            const int gi   = nwi ? (ls?0:1) : c1;
            const int new_s= grab ? gi+1 : (hasc ? s : 0);
            const float* Rk = rb + 9*k;
            const float* Hk = hb + 6*k;
            if (grab) {
                const float hx = gi?Hk[3]:Hk[0], hy = gi?Hk[4]:Hk[1], hz = gi?Hk[5]:Hk[2];
                // Wmap <- R^T o pmap; cw = R^T (cp - h); rw = rp  (p'~=p approx)
                float t[9];
                #pragma unroll
                for (int i2=0;i2<3;++i2)
                    #pragma unroll
                    for (int j2=0;j2<3;++j2)
                        t[3*i2+j2] = Rk[i2]*Am[j2] + Rk[3+i2]*Am[3+j2] + Rk[6+i2]*Am[6+j2];
                const float ex=Am[9]-hx, ey=Am[10]-hy, ez=Am[11]-hz;
                Am[21] = Rk[0]*ex + Rk[3]*ey + Rk[6]*ez;
                Am[22] = Rk[1]*ex + Rk[4]*ey + Rk[7]*ez;
                Am[23] = Rk[2]*ex + Rk[5]*ey + Rk[8]*ez;
                #pragma unroll
                for (int i2=0;i2<9;++i2) Am[12+i2] = t[i2];
                rw = rp;
            } else if (new_s) {
                const int ci = new_s - 1;
                const float hx = ci?Hk[3]:Hk[0], hy = ci?Hk[4]:Hk[1], hz = ci?Hk[5]:Hk[2];
                // pmap <- h + R o Wmap; rp = rw
                float t[9];
                #pragma unroll
                for (int i2=0;i2<3;++i2)
                    #pragma unroll
                    for (int j2=0;j2<3;++j2)
                        t[3*i2+j2] = Rk[3*i2]*Am[12+j2] + Rk[3*i2+1]*Am[15+j2] + Rk[3*i2+2]*Am[18+j2];
                const float e0_ = hx + Rk[0]*Am[21] + Rk[1]*Am[22] + Rk[2]*Am[23];
                const float e1_ = hy + Rk[3]*Am[21] + Rk[4]*Am[22] + Rk[5]*Am[23];
                const float e2_ = hz + Rk[6]*Am[21] + Rk[7]*Am[22] + Rk[8]*Am[23];
                #pragma unroll
                for (int i2=0;i2<9;++i2) Am[i2] = t[i2];
                Am[9]=e0_; Am[10]=e1_; Am[11]=e2_;
                rp = rw;
            }
            s = new_s;
        }
    }

    // ---------------- affine KS scan (select-based, r7 codegen) ------------
    #pragma unroll 1
    for (int d = 1; d < 64; d <<= 1) {
        float Em[24];
        #pragma unroll
        for (int i = 0; i < 24; ++i) Em[i] = __shfl_up(Am[i], d);
        const int Ef = __shfl_up(rp | (rw<<1), d);
        float Om[24]; int orp, orw;
        tmap_compose(Am, rp, rw, Em, Ef&1, (Ef>>1)&1, Om, orp, orw);
        const bool act = (lane >= d);
        #pragma unroll
        for (int i = 0; i < 24; ++i) Am[i] = act ? Om[i] : Am[i];
        rp = act ? orp : rp;
        rw = act ? orw : rw;
    }
    if (lane == 63) {
        #pragma unroll
        for (int i = 0; i < 24; ++i) sAm[w][i] = Am[i];
        sAf[w] = rp | (rw<<1);
    }
    __syncthreads();

    // exclusive shift in place
    {
        #pragma unroll
        for (int i = 0; i < 24; ++i) Am[i] = __shfl_up(Am[i], 1);
        const int t = __shfl_up(rp | (rw<<1), 1);
        int nrp = t & 1, nrw = (t >> 1) & 1;
        if (lane == 0) tmap_identity(Am, nrp, nrw);
        rp = nrp; rw = nrw;
        if (lane == 0) { rp = 0; rw = 1; }
    }

    // wave prefix applied to the concrete state vector (p0=tinit, W0=0)
    float vp[3] = { tinit[3*b], tinit[3*b+1], tinit[3*b+2] };
    float vw[3] = { 0.f, 0.f, 0.f };
    for (int i = 0; i < w; ++i) {
        float np[3], nw2[3];
        const int f = sAf[i];
        tmap_apply(&sAm[i][0], f & 1, (f >> 1) & 1, vp, vw, np, nw2);
        vp[0]=np[0]; vp[1]=np[1]; vp[2]=np[2];
        vw[0]=nw2[0]; vw[1]=nw2[1]; vw[2]=nw2[2];
    }
    float pv[3], wv[3];
    tmap_apply(Am, rp, rw, vp, vw, pv, wv);
    float px = pv[0], py = pv[1], pz = pv[2];
    float Wx = wv[0], Wy = wv[1], Wz = wv[2];

    // ---------------- P3: exact replay + output ----------------
    s = s_in;
    {
        float rb[36], hb[24];
        #pragma unroll
        for (int j = 0; j < 9; ++j) {
            float4 v = rm4[j];
            rb[4*j]=v.x; rb[4*j+1]=v.y; rb[4*j+2]=v.z; rb[4*j+3]=v.w;
        }
        #pragma unroll
        for (int j = 0; j < 6; ++j) {
            float4 v = hd4[j];
            hb[4*j]=v.x; hb[4*j+1]=v.y; hb[4*j+2]=v.z; hb[4*j+3]=v.w;
        }
        float o[12];
        #pragma unroll
        for (int k = 0; k < 4; ++k) {
            const unsigned lc=(lcB>>k)&1u, rc=(rcB>>k)&1u;
            const unsigned ls=(lsB>>k)&1u, rs=(rsB>>k)&1u;
            const int nwi  = (int)(ls|rs);
            const int c1 = (s==1), c2 = (s==2);
            const int hasc = (c1&(int)lc)|(c2&(int)rc);
            const int haso = (c1&(int)rc)|(c2&(int)lc);
            const int grab = nwi | ((hasc^1)&haso);
            const int gi   = nwi ? (ls?0:1) : c1;
            const int new_s= grab ? gi+1 : (hasc ? s : 0);
            const float* Rk = rb + 9*k;
            const float* Hk = hb + 6*k;
            if (grab) {
                const float hx = gi?Hk[3]:Hk[0], hy = gi?Hk[4]:Hk[1], hz = gi?Hk[5]:Hk[2];
                const float vx = px-hx, vy = py-hy, vz = pz-hz;
                const float d2 = vx*vx + vy*vy + vz*vz;
                if (d2 > 1e-12f) {
                    Wx = Rk[0]*vx + Rk[3]*vy + Rk[6]*vz;
                    Wy = Rk[1]*vx + Rk[4]*vy + Rk[7]*vz;
                    Wz = Rk[2]*vx + Rk[5]*vy + Rk[8]*vz;
                } else {
                    Wx = 0.1f*Rk[6]; Wy = 0.1f*Rk[7]; Wz = 0.1f*Rk[8];
                }
            }
            if (new_s) {
                const int ci = new_s - 1;
                const float hx = ci?Hk[3]:Hk[0], hy = ci?Hk[4]:Hk[1], hz = ci?Hk[5]:Hk[2];
                px = hx + Rk[0]*Wx + Rk[1]*Wy + Rk[2]*Wz;
                py = hy + Rk[3]*Wx + Rk[4]*Wy + Rk[5]*Wz;
                pz = hz + Rk[6]*Wx + Rk[7]*Wy + Rk[8]*Wz;
            }
            s = new_s;
            o[3*k+0]=px; o[3*k+1]=py; o[3*k+2]=pz;
        }
        ob4[0] = make_float4(o[0], o[1], o[2],  o[3]);
        ob4[1] = make_float4(o[4], o[5], o[6],  o[7]);
        ob4[2] = make_float4(o[8], o[9], o[10], o[11]);
    }
}

// ---------------- fallback (any T): wave-per-batch serial scan -----
#define CT 256
__global__ __launch_bounds__(64) void fk_scan_wave(
    const float* __restrict__ prob, const float* __restrict__ hands,
    const float* __restrict__ rotm, const float* __restrict__ tinit,
    float* __restrict__ out, int B, int T)
{
    __shared__ __align__(16) float sP[CT * 2];
    __shared__ __align__(16) float sH[CT * 8];
    __shared__ __align__(16) float sR[CT * 12];
    const int b = blockIdx.x, lane = threadIdx.x;
    const float* prB = prob  + (size_t)b * T * 2;
    const float* hdB = hands + (size_t)b * T * 6;
    const float* rmB = rotm  + (size_t)b * T * 9;
    float*       obB = out   + (size_t)b * T * 3;
    float px = tinit[3*b+0], py = tinit[3*b+1], pz = tinit[3*b+2];
    float Wx = 0.f, Wy = 0.f, Wz = 0.f;
    int cur = -1, prev_l = 0, prev_r = 0;
    for (int t0 = 0; t0 < T; t0 += CT) {
        const int n = (T - t0 < CT) ? (T - t0) : CT;
        for (int i = lane; i < n * 2; i += 64) sP[i] = prB[(size_t)t0*2 + i];
        for (int i = lane; i < n * 6; i += 64) {
            int s2 = i / 6, cc = i - 6*s2; sH[8*s2+cc] = hdB[(size_t)t0*6 + i];
        }
        for (int i = lane; i < n * 9; i += 64) {
            int s2 = i / 9, cc = i - 9*s2; sR[12*s2+cc] = rmB[(size_t)t0*9 + i];
        }
        __syncthreads();
        for (int k = 0; k < n; ++k) {
            const int t = t0 + k;
            const int rl = __builtin_amdgcn_readfirstlane(sP[2*k]   > 0.5f ? 1 : 0);
            const int rr = __builtin_amdgcn_readfirstlane(sP[2*k+1] > 0.5f ? 1 : 0);
            const int nz = (t != 0) ? 1 : 0;
            const int l_c = rl & nz, r_c = rr & nz;
            const int l_s = rl & (prev_l ^ 1) & nz, r_s = rr & (prev_r ^ 1) & nz;
            prev_l = rl; prev_r = rr;
            const int nw = l_s ? 0 : (r_s ? 1 : -1);
            const int hasc = ((cur==0)&l_c) | ((cur==1)&r_c);
            const int haso = ((cur==0)&r_c) | ((cur==1)&l_c);
            const int grab = (nw != -1) | ((hasc^1)&haso);
            const int new_cur = grab ? ((nw!=-1)?nw:(1-cur))
                                     : (((hasc^1)&(cur!=-1)) ? -1 : cur);
            if (new_cur != -1) {
                const float h0x=sH[8*k+0],h0y=sH[8*k+1],h0z=sH[8*k+2];
                const float h1x=sH[8*k+3],h1y=sH[8*k+4],h1z=sH[8*k+5];
                const float R0=sR[12*k+0],R1=sR[12*k+1],R2=sR[12*k+2];
                const float R3=sR[12*k+3],R4=sR[12*k+4],R5=sR[12*k+5];
                const float R6=sR[12*k+6],R7=sR[12*k+7],R8=sR[12*k+8];
                const float hx = new_cur ? h1x : h0x;
                const float hy = new_cur ? h1y : h0y;
                const float hz = new_cur ? h1z : h0z;
                if (grab) {
                    const float vx=px-hx, vy=py-hy, vz=pz-hz;
                    const float d2 = vx*vx+vy*vy+vz*vz;
                    if (d2 > 1e-12f) {
                        Wx = R0*vx+R3*vy+R6*vz; Wy = R1*vx+R4*vy+R7*vz; Wz = R2*vx+R5*vy+R8*vz;
                    } else { Wx = 0.1f*R6; Wy = 0.1f*R7; Wz = 0.1f*R8; }
                }
                px = hx + (R0*Wx+R1*Wy+R2*Wz);
                py = hy + (R3*Wx+R4*Wy+R5*Wz);
                pz = hz + (R6*Wx+R7*Wy+R8*Wz);
            }
            cur = new_cur;
            if (lane == 0) {
                obB[3*(size_t)t+0]=px; obB[3*(size_t)t+1]=py; obB[3*(size_t)t+2]=pz;
            }
        }
        __syncthreads();
    }
}

extern "C" void kernel_launch(void* const* d_in, const int* in_sizes, int n_in,
                              void* d_out, int out_size, void* d_ws, size_t ws_size,
                              hipStream_t stream) {
    const float* prob  = (const float*)d_in[0];
    const float* hands = (const float*)d_in[1];
    const float* rotm  = (const float*)d_in[2];
    const float* tinit = (const float*)d_in[3];
    float* out = (float*)d_out;

    const int B = in_sizes[3] / 3;
    const int T = in_sizes[0] / (B * 2);

    if (T == 4096) {
        hipLaunchKernelGGL(fk_scan_par5, dim3(B), dim3(1024), 0, stream,
                           prob, hands, rotm, tinit, out);
    } else {
        hipLaunchKernelGGL(fk_scan_wave, dim3(B), dim3(64), 0, stream,
                           prob, hands, rotm, tinit, out, B, T);
    }
}